// Round 2
// baseline (159.340 us; speedup 1.0000x reference)
//
#include <hip/hip_runtime.h>
#include <hip/hip_bf16.h>

// SeqChamferLoss: B=4, C=3, T=16, N=2048, fp32 in, scalar fp32 out.
// loss = mean over (b,t) of [ sum_m min_n d2(x_n,y_m) + sum_n min_m d2(x_n,y_m) ]
// x = gts, y = preds, planes [B,C,T,N].
//
// Strategy (R2): VALU-bound. Cut instr/pair from 4 to ~2 via paired refs
// (v_pk_fma_f32) + v_min3_f32, and stream refs through the SMEM pipe
// (uniform s_load from a pre-packed workspace) instead of LDS.

#define BV 4
#define CV 3
#define TV 16
#define NV 2048
#define PS (TV * NV)        // plane stride between consecutive c for fixed (b,t)
#define NPAIR (NV / 2)      // 1024 ref pairs
#define THREADS 256
#define QPT 2               // queries per thread -> 512 queries per block
#define QCHUNK 4            // 4 * 512 = 2048 queries per (bt,dir)

// ---------------------------------------------------------------------------
// Kernel 1: pack refs for both directions into d_ws.
// Layout: for (dir,bt,pair p): two float4s
//   [0] = (-2x0, -2x1, -2y0, -2y1)
//   [1] = (-2z0, -2z1,  w0,   w1)   where w = ||r||^2
// Total: 2 * 64 * 1024 * 32 B = 4 MB (L2-resident).
// ---------------------------------------------------------------------------
__global__ __launch_bounds__(256)
void pack_kernel(const float* __restrict__ preds,
                 const float* __restrict__ gts,
                 float4* __restrict__ ws)
{
    int idx = blockIdx.x * 256 + threadIdx.x;   // 0 .. 2*64*1024-1
    int p   = idx & (NPAIR - 1);                // bits 0..9
    int bt  = (idx >> 10) & 63;                 // bits 10..15
    int dir = idx >> 16;                        // 0: refs=gts, 1: refs=preds
    const float* src = dir ? preds : gts;
    int b = bt >> 4, t = bt & (TV - 1);
    const float* s0 = src + ((size_t)b * CV * TV + t) * NV;

    float2 x = ((const float2*)(s0))[p];
    float2 y = ((const float2*)(s0 + PS))[p];
    float2 z = ((const float2*)(s0 + 2 * PS))[p];
    float w0 = fmaf(x.x, x.x, fmaf(y.x, y.x, z.x * z.x));
    float w1 = fmaf(x.y, x.y, fmaf(y.y, y.y, z.y * z.y));

    float4* dst = ws + ((size_t)(dir * 64 + bt) * NPAIR + p) * 2;
    dst[0] = make_float4(-2.0f * x.x, -2.0f * x.y, -2.0f * y.x, -2.0f * y.y);
    dst[1] = make_float4(-2.0f * z.x, -2.0f * z.y, w0, w1);
}

// ---------------------------------------------------------------------------
// Kernel 2: per (bt, dir, query-chunk) block; each thread owns QPT queries
// and scans all 1024 ref-pairs. Ref loads are loop-uniform -> SMEM (s_load).
// ---------------------------------------------------------------------------
__global__ __launch_bounds__(THREADS)
void chamfer_kernel(const float* __restrict__ preds,
                    const float* __restrict__ gts,
                    const float4* __restrict__ ws,
                    float* __restrict__ out)
{
    int blk = blockIdx.x;                 // ((bt*2 + dir)*QCHUNK + qc)
    int qc  = blk & (QCHUNK - 1);
    int dir = (blk >> 2) & 1;
    int bt  = blk >> 3;
    int b = bt >> 4, t = bt & (TV - 1);

    // dir 0: queries = preds, refs = gts (loss_1); dir 1: swapped (loss_2)
    const float* qbase = dir ? gts : preds;
    const float* q0 = qbase + ((size_t)b * CV * TV + t) * NV;
    const float4* __restrict__ rp = ws + (size_t)(dir * 64 + bt) * NPAIR * 2;

    float qx[QPT], qy[QPT], qz[QPT], rq[QPT], acc[QPT];
    const int m0 = qc * (THREADS * QPT) + threadIdx.x;
#pragma unroll
    for (int k = 0; k < QPT; ++k) {
        int m = m0 + k * THREADS;
        qx[k] = q0[m];
        qy[k] = q0[PS + m];
        qz[k] = q0[2 * PS + m];
        rq[k] = fmaf(qx[k], qx[k], fmaf(qy[k], qy[k], qz[k] * qz[k]));
        acc[k] = 3.4e38f;
    }

    // main loop: 1024 ref pairs, uniform loads (SMEM), paired FMAs (pk_fma),
    // min3 accumulate.
#pragma unroll 4
    for (int n = 0; n < NPAIR; ++n) {
        float4 A = rp[2 * n];       // -2x0 -2x1 -2y0 -2y1
        float4 B = rp[2 * n + 1];   // -2z0 -2z1  w0   w1
#pragma unroll
        for (int k = 0; k < QPT; ++k) {
            float d0 = fmaf(A.x, qx[k], B.z);
            float d1 = fmaf(A.y, qx[k], B.w);
            d0 = fmaf(A.z, qy[k], d0);
            d1 = fmaf(A.w, qy[k], d1);
            d0 = fmaf(B.x, qz[k], d0);
            d1 = fmaf(B.y, qz[k], d1);
            acc[k] = fminf(fminf(acc[k], d0), d1);   // -> v_min3_f32
        }
    }

    // per-thread sum of (min + ||q||^2)
    float s = 0.0f;
#pragma unroll
    for (int k = 0; k < QPT; ++k) s += acc[k] + rq[k];

    // block reduction: wave shuffle then LDS across 4 waves
#pragma unroll
    for (int o = 32; o > 0; o >>= 1) s += __shfl_down(s, o, 64);

    __shared__ float red[THREADS / 64];
    int wid  = threadIdx.x >> 6;
    int lane = threadIdx.x & 63;
    if (lane == 0) red[wid] = s;
    __syncthreads();
    if (threadIdx.x == 0) {
        float tot = red[0] + red[1] + red[2] + red[3];
        atomicAdd(out, tot * (1.0f / (BV * TV)));
    }
}

extern "C" void kernel_launch(void* const* d_in, const int* in_sizes, int n_in,
                              void* d_out, int out_size, void* d_ws, size_t ws_size,
                              hipStream_t stream) {
    const float* preds = (const float*)d_in[0];
    const float* gts   = (const float*)d_in[1];
    float* out = (float*)d_out;
    float4* ws = (float4*)d_ws;   // needs 4 MB; harness scratch is larger

    // zero the scalar accumulator (harness poisons d_out with 0xAA)
    hipMemsetAsync(out, 0, sizeof(float), stream);

    // pack refs (both dirs): 2*64*1024 pairs, one per thread
    pack_kernel<<<(2 * 64 * NPAIR) / 256, 256, 0, stream>>>(preds, gts, ws);

    const int nblocks = BV * TV * 2 * QCHUNK;   // 512
    chamfer_kernel<<<nblocks, THREADS, 0, stream>>>(preds, gts, ws, out);
}

// Round 3
// 87.028 us; speedup vs baseline: 1.8309x; 1.8309x over previous
//
#include <hip/hip_runtime.h>
#include <hip/hip_bf16.h>

// SeqChamferLoss: B=4, C=3, T=16, N=2048, fp32 in, scalar fp32 out.
// loss = mean over (b,t) of [ sum_m min_n d2 + sum_n min_m d2 ], x=gts, y=preds.
//
// R3: MFMA formulation. Per 32x32 tile, one v_mfma_f32_32x32x16_bf16 computes
// M[n,m] = -2 x_n . y_m + rx[n]  exactly (bf16 hi/lo split, K=12 cross terms,
// K-slots 12/13 carry rx via B-side 1.0). VALU only does the min-fold.
// colmin_m = min_n M[n,m]; result_m = colmin_m + ry[m]; sum, scale 1/64.

typedef short short8 __attribute__((ext_vector_type(8)));
typedef float f32x16 __attribute__((ext_vector_type(16)));

#define BV 4
#define CV 3
#define TV 16
#define NV 2048
#define PS (TV * NV)     // plane stride between c for fixed (b,t)
#define THREADS 256
#define NT 64            // 2048/32 ref tiles
#define MPW 4            // query (m) tiles per wave

static __device__ inline short bfh(float v) {
    __hip_bfloat16 h = __float2bfloat16(v);
    return *reinterpret_cast<short*>(&h);
}
static __device__ inline float bff(short s) {
    __hip_bfloat16 h;
    *reinterpret_cast<short*>(&h) = s;
    return __bfloat162float(h);
}
static __device__ inline void split2(float v, short& hi, short& lo) {
    short h = bfh(v);
    hi = h;
    lo = bfh(v - bff(h));
}

__global__ __launch_bounds__(THREADS)
void chamfer_kernel(const float* __restrict__ preds,
                    const float* __restrict__ gts,
                    float* __restrict__ out)
{
    // A-side fragments, fragment-linear: [tile nt][64 lane-slots] of 16B.
    // lane l of tile nt reads afr[nt*64 + l]: point = nt*32 + (l&31),
    // k-slots (l>>5)*8 .. +7.
    __shared__ short8 afr[NT * 64];          // 64 KB
    __shared__ float red[THREADS / 64];

    const int tid  = threadIdx.x;
    const int lane = tid & 63;
    const int wid  = tid >> 6;
    const int col  = lane & 31;
    const int half = lane >> 5;

    const int blk = blockIdx.x;              // 512 = slice(64) x dir(2) x q(4)
    const int q   = blk & 3;
    const int dir = (blk >> 2) & 1;
    const int sl  = blk >> 3;
    const int b   = sl >> 4, t = sl & 15;

    const size_t base = ((size_t)b * CV * TV + t) * NV;
    // dir0: refs = gts (loss_1: min over Nx), queries = preds
    // dir1: refs = preds (loss_2), queries = gts
    const float* rsrc = (dir ? preds : gts) + base;
    const float* qsrc = (dir ? gts : preds) + base;

    // ---- build A-side (ref) fragments into LDS ----
    // K pattern A: [sh0,sh1,sh2,sh0,sh1,sh2,sl0,sl1 | sl2,sl0,sl1,sl2,rxh,rxl,0,0]
    // K pattern B: [yh0,yh1,yh2,yl0,yl1,yl2,yh0,yh1 | yh2,yl0,yl1,yl2, 1 , 1 ,0,0]
    // dot = (sh+sl).(yh+yl) + rx = -2x.y + rx   (s = -2x)
#pragma unroll
    for (int i = 0; i < 8; ++i) {
        int p = tid + THREADS * i;           // point index, coalesced
        float x0 = rsrc[p], x1 = rsrc[PS + p], x2 = rsrc[2 * PS + p];
        float rx = fmaf(x0, x0, fmaf(x1, x1, x2 * x2));
        short sh0, sl0, sh1, sl1, sh2, sl2, rh, rl;
        split2(-2.f * x0, sh0, sl0);
        split2(-2.f * x1, sh1, sl1);
        split2(-2.f * x2, sh2, sl2);
        split2(rx, rh, rl);
        short8 h0, h1;
        h0[0] = sh0; h0[1] = sh1; h0[2] = sh2; h0[3] = sh0;
        h0[4] = sh1; h0[5] = sh2; h0[6] = sl0; h0[7] = sl1;
        h1[0] = sl2; h1[1] = sl0; h1[2] = sl1; h1[3] = sl2;
        h1[4] = rh;  h1[5] = rl;  h1[6] = 0;   h1[7] = 0;
        int slot = (p >> 5) * 64 + (p & 31);
        afr[slot]      = h0;                 // k 0..7 half (lanes 0-31)
        afr[slot + 32] = h1;                 // k 8..15 half (lanes 32-63)
    }

    // ---- build B-side (query) fragments in registers ----
    short8 bfr[MPW];
    float  ry[MPW];
    const short ONE = 0x3F80;                // bf16 1.0
#pragma unroll
    for (int j = 0; j < MPW; ++j) {
        int mt = q * 16 + wid * 4 + j;       // m-tile, covers 0..63
        int m  = mt * 32 + col;
        float y0 = qsrc[m], y1 = qsrc[PS + m], y2 = qsrc[2 * PS + m];
        ry[j] = fmaf(y0, y0, fmaf(y1, y1, y2 * y2));
        short yh0, yl0, yh1, yl1, yh2, yl2;
        split2(y0, yh0, yl0);
        split2(y1, yh1, yl1);
        split2(y2, yh2, yl2);
        short8 f;
        if (half == 0) {
            f[0] = yh0; f[1] = yh1; f[2] = yh2; f[3] = yl0;
            f[4] = yl1; f[5] = yl2; f[6] = yh0; f[7] = yh1;
        } else {
            f[0] = yh2; f[1] = yl0; f[2] = yl1; f[3] = yl2;
            f[4] = ONE; f[5] = ONE; f[6] = 0;   f[7] = 0;
        }
        bfr[j] = f;
    }
    __syncthreads();

    // ---- main loop: 64 ref tiles x MPW MFMAs, min-fold into acc ----
    float acc[MPW] = {3.4e38f, 3.4e38f, 3.4e38f, 3.4e38f};
    f32x16 zc = {};                          // permanent zero C-operand
#pragma unroll 8
    for (int nt = 0; nt < NT; ++nt) {
        short8 a = afr[nt * 64 + lane];      // ds_read_b128, conflict-free
#pragma unroll
        for (int j = 0; j < MPW; ++j) {
            f32x16 d = __builtin_amdgcn_mfma_f32_32x32x16_bf16(a, bfr[j], zc, 0, 0, 0);
            float mn = acc[j];
#pragma unroll
            for (int e = 0; e < 16; e += 2)
                mn = fminf(fminf(mn, d[e]), d[e + 1]);   // v_min3 chain
            acc[j] = mn;
        }
    }

    // ---- reductions ----
    // D col = lane&31; lanes l and l+32 hold the two row-halves of col l&31.
    float wsum = 0.f;
#pragma unroll
    for (int j = 0; j < MPW; ++j) {
        float v = acc[j];
        v = fminf(v, __shfl_xor(v, 32, 64)); // complete colmin over all 32 rows/lane-halves
        wsum += v + ry[j];                   // duplicated in both halves -> x2
    }
#pragma unroll
    for (int o = 32; o > 0; o >>= 1) wsum += __shfl_down(wsum, o, 64);
    if (lane == 0) red[wid] = wsum;
    __syncthreads();
    if (tid == 0)
        atomicAdd(out, (red[0] + red[1] + red[2] + red[3]) * (0.5f / (BV * TV)));
}

extern "C" void kernel_launch(void* const* d_in, const int* in_sizes, int n_in,
                              void* d_out, int out_size, void* d_ws, size_t ws_size,
                              hipStream_t stream) {
    const float* preds = (const float*)d_in[0];
    const float* gts   = (const float*)d_in[1];
    float* out = (float*)d_out;

    hipMemsetAsync(out, 0, sizeof(float), stream);

    const int nblocks = 64 * 2 * 4;          // slice x dir x q = 512, 2 blocks/CU
    chamfer_kernel<<<nblocks, THREADS, 0, stream>>>(preds, gts, out);
}

// Round 4
// 84.467 us; speedup vs baseline: 1.8864x; 1.0303x over previous
//
#include <hip/hip_runtime.h>
#include <hip/hip_bf16.h>

// SeqChamferLoss: B=4, C=3, T=16, N=2048, fp32 in, scalar fp32 out.
// loss = mean over (b,t) of [ sum_m min_n d2 + sum_n min_m d2 ], x=gts, y=preds.
//
// R4: same MFMA formulation as R3 (exact bf16 hi/lo split, one
// v_mfma_f32_32x32x16_bf16 per 32x32 tile computing -2x.y + rx), but:
//   - per-block partials into d_ws + 1-block finish kernel
//     (R3 suspect: 512 serialized same-address atomicAdds = kernel tail)
//   - unroll 4 (R3 suspect #2: unroll-8 register pressure)

typedef short short8 __attribute__((ext_vector_type(8)));
typedef float f32x16 __attribute__((ext_vector_type(16)));

#define BV 4
#define CV 3
#define TV 16
#define NV 2048
#define PS (TV * NV)     // plane stride between c for fixed (b,t)
#define THREADS 256
#define NT 64            // 2048/32 ref tiles
#define MPW 4            // query (m) tiles per wave
#define NBLK 512         // slice(64) x dir(2) x q(4)

static __device__ inline short bfh(float v) {
    __hip_bfloat16 h = __float2bfloat16(v);
    return *reinterpret_cast<short*>(&h);
}
static __device__ inline float bff(short s) {
    __hip_bfloat16 h;
    *reinterpret_cast<short*>(&h) = s;
    return __bfloat162float(h);
}
static __device__ inline void split2(float v, short& hi, short& lo) {
    short h = bfh(v);
    hi = h;
    lo = bfh(v - bff(h));
}

__global__ __launch_bounds__(THREADS)
void chamfer_kernel(const float* __restrict__ preds,
                    const float* __restrict__ gts,
                    float* __restrict__ partial)
{
    // A-side fragments, fragment-linear: [tile nt][64 lane-slots] of 16B.
    __shared__ short8 afr[NT * 64];          // 64 KB
    __shared__ float red[THREADS / 64];

    const int tid  = threadIdx.x;
    const int lane = tid & 63;
    const int wid  = tid >> 6;
    const int col  = lane & 31;
    const int half = lane >> 5;

    const int blk = blockIdx.x;
    const int q   = blk & 3;
    const int dir = (blk >> 2) & 1;
    const int sl  = blk >> 3;
    const int b   = sl >> 4, t = sl & 15;

    const size_t base = ((size_t)b * CV * TV + t) * NV;
    const float* rsrc = (dir ? preds : gts) + base;   // refs
    const float* qsrc = (dir ? gts : preds) + base;   // queries

    // ---- build A-side (ref) fragments into LDS ----
    // K pattern A: [sh0,sh1,sh2,sh0,sh1,sh2,sl0,sl1 | sl2,sl0,sl1,sl2,rxh,rxl,0,0]
    // K pattern B: [yh0,yh1,yh2,yl0,yl1,yl2,yh0,yh1 | yh2,yl0,yl1,yl2, 1 , 1 ,0,0]
#pragma unroll
    for (int i = 0; i < 8; ++i) {
        int p = tid + THREADS * i;
        float x0 = rsrc[p], x1 = rsrc[PS + p], x2 = rsrc[2 * PS + p];
        float rx = fmaf(x0, x0, fmaf(x1, x1, x2 * x2));
        short sh0, sl0, sh1, sl1, sh2, sl2, rh, rl;
        split2(-2.f * x0, sh0, sl0);
        split2(-2.f * x1, sh1, sl1);
        split2(-2.f * x2, sh2, sl2);
        split2(rx, rh, rl);
        short8 h0, h1;
        h0[0] = sh0; h0[1] = sh1; h0[2] = sh2; h0[3] = sh0;
        h0[4] = sh1; h0[5] = sh2; h0[6] = sl0; h0[7] = sl1;
        h1[0] = sl2; h1[1] = sl0; h1[2] = sl1; h1[3] = sl2;
        h1[4] = rh;  h1[5] = rl;  h1[6] = 0;   h1[7] = 0;
        int slot = (p >> 5) * 64 + (p & 31);
        afr[slot]      = h0;
        afr[slot + 32] = h1;
    }

    // ---- B-side (query) fragments in registers ----
    short8 bfr[MPW];
    float  ry[MPW];
    const short ONE = 0x3F80;                // bf16 1.0
#pragma unroll
    for (int j = 0; j < MPW; ++j) {
        int mt = q * 16 + wid * 4 + j;
        int m  = mt * 32 + col;
        float y0 = qsrc[m], y1 = qsrc[PS + m], y2 = qsrc[2 * PS + m];
        ry[j] = fmaf(y0, y0, fmaf(y1, y1, y2 * y2));
        short yh0, yl0, yh1, yl1, yh2, yl2;
        split2(y0, yh0, yl0);
        split2(y1, yh1, yl1);
        split2(y2, yh2, yl2);
        short8 f;
        if (half == 0) {
            f[0] = yh0; f[1] = yh1; f[2] = yh2; f[3] = yl0;
            f[4] = yl1; f[5] = yl2; f[6] = yh0; f[7] = yh1;
        } else {
            f[0] = yh2; f[1] = yl0; f[2] = yl1; f[3] = yl2;
            f[4] = ONE; f[5] = ONE; f[6] = 0;   f[7] = 0;
        }
        bfr[j] = f;
    }
    __syncthreads();

    // ---- main loop ----
    float acc[MPW] = {3.4e38f, 3.4e38f, 3.4e38f, 3.4e38f};
    f32x16 zc = {};
#pragma unroll 4
    for (int nt = 0; nt < NT; ++nt) {
        short8 a = afr[nt * 64 + lane];
#pragma unroll
        for (int j = 0; j < MPW; ++j) {
            f32x16 d = __builtin_amdgcn_mfma_f32_32x32x16_bf16(a, bfr[j], zc, 0, 0, 0);
            float mn = acc[j];
#pragma unroll
            for (int e = 0; e < 16; e += 2)
                mn = fminf(fminf(mn, d[e]), d[e + 1]);
            acc[j] = mn;
        }
    }

    // ---- reductions ----
    float wsum = 0.f;
#pragma unroll
    for (int j = 0; j < MPW; ++j) {
        float v = acc[j];
        v = fminf(v, __shfl_xor(v, 32, 64));
        wsum += v + ry[j];                   // both halves identical -> x2
    }
#pragma unroll
    for (int o = 32; o > 0; o >>= 1) wsum += __shfl_down(wsum, o, 64);
    if (lane == 0) red[wid] = wsum;
    __syncthreads();
    if (tid == 0)
        partial[blk] = red[0] + red[1] + red[2] + red[3];
}

// one block: sum 512 partials, scale by 0.5 (half duplication) / 64 (mean)
__global__ __launch_bounds__(THREADS)
void finish_kernel(const float* __restrict__ partial, float* __restrict__ out)
{
    __shared__ float red[THREADS / 64];
    const int tid = threadIdx.x;
    float s = partial[tid] + partial[tid + THREADS];
#pragma unroll
    for (int o = 32; o > 0; o >>= 1) s += __shfl_down(s, o, 64);
    if ((tid & 63) == 0) red[tid >> 6] = s;
    __syncthreads();
    if (tid == 0)
        out[0] = (red[0] + red[1] + red[2] + red[3]) * (1.0f / 128.0f);
}

extern "C" void kernel_launch(void* const* d_in, const int* in_sizes, int n_in,
                              void* d_out, int out_size, void* d_ws, size_t ws_size,
                              hipStream_t stream) {
    const float* preds = (const float*)d_in[0];
    const float* gts   = (const float*)d_in[1];
    float* out = (float*)d_out;
    float* partial = (float*)d_ws;

    chamfer_kernel<<<NBLK, THREADS, 0, stream>>>(preds, gts, partial);
    finish_kernel<<<1, THREADS, 0, stream>>>(partial, out);
}

// Round 5
// 75.403 us; speedup vs baseline: 2.1132x; 1.1202x over previous
//
#include <hip/hip_runtime.h>
#include <hip/hip_bf16.h>

// SeqChamferLoss: B=4, C=3, T=16, N=2048, fp32 in, scalar fp32 out.
// loss = mean over (b,t) of [ sum_m min_n d2 + sum_n min_m d2 ], x=gts, y=preds.
//
// R5: same exact-MFMA formulation (bf16 hi/lo split, one
// v_mfma_f32_32x32x16_bf16 per 32x32 tile computing -2x.y + rx), but split
// each ref range across 2 blocks: 1024 blocks, 32 KB LDS -> 4 blocks/CU
// (4 waves/SIMD, was 2) for MFMA-pipe latency hiding. Per-query partial
// mins (+||q||^2) to d_ws; finishA/finishB reduce.

typedef short short8 __attribute__((ext_vector_type(8)));
typedef float f32x16 __attribute__((ext_vector_type(16)));

#define BV 4
#define CV 3
#define TV 16
#define NV 2048
#define PS (TV * NV)     // plane stride between c for fixed (b,t)
#define THREADS 256
#define NT 32            // ref tiles per block (half of 2048/32)
#define MPW 4            // query (m) tiles per wave
#define NBLK 1024        // sl(64) x dir(2) x q(4) x rhalf(2)
#define NCHUNK 512       // sl x dir x q query-chunks
#define PQ (NCHUNK * 2 * 512)   // partial-min floats in ws (524288)

static __device__ inline short bfh(float v) {
    __hip_bfloat16 h = __float2bfloat16(v);
    return *reinterpret_cast<short*>(&h);
}
static __device__ inline float bff(short s) {
    __hip_bfloat16 h;
    *reinterpret_cast<short*>(&h) = s;
    return __bfloat162float(h);
}
static __device__ inline void split2(float v, short& hi, short& lo) {
    short h = bfh(v);
    hi = h;
    lo = bfh(v - bff(h));
}

__global__ __launch_bounds__(THREADS, 4)
void chamfer_kernel(const float* __restrict__ preds,
                    const float* __restrict__ gts,
                    float* __restrict__ pmin)
{
    // A-side fragments, fragment-linear: [tile nt][64 lane-slots] of 16B.
    __shared__ short8 afr[NT * 64];          // 32 KB -> 4 blocks/CU

    const int tid  = threadIdx.x;
    const int lane = tid & 63;
    const int wid  = tid >> 6;
    const int col  = lane & 31;
    const int half = lane >> 5;

    const int blk = blockIdx.x;              // ((sl*2+dir)*4+q)*2 + rh
    const int rh  = blk & 1;
    const int q   = (blk >> 1) & 3;
    const int dir = (blk >> 3) & 1;
    const int sl  = blk >> 4;
    const int b   = sl >> 4, t = sl & 15;

    const size_t base = ((size_t)b * CV * TV + t) * NV;
    const float* rsrc = (dir ? preds : gts) + base;   // refs
    const float* qsrc = (dir ? gts : preds) + base;   // queries

    // ---- build A-side (ref) fragments into LDS (this block's 1024 refs) ----
    // K pattern A: [sh0,sh1,sh2,sh0,sh1,sh2,sl0,sl1 | sl2,sl0,sl1,sl2,rxh,rxl,0,0]
    // K pattern B: [yh0,yh1,yh2,yl0,yl1,yl2,yh0,yh1 | yh2,yl0,yl1,yl2, 1 , 1 ,0,0]
#pragma unroll
    for (int i = 0; i < 4; ++i) {
        int p  = tid + THREADS * i;          // 0..1023 within this half
        int rp = rh * 1024 + p;              // point index within slice
        float x0 = rsrc[rp], x1 = rsrc[PS + rp], x2 = rsrc[2 * PS + rp];
        float rx = fmaf(x0, x0, fmaf(x1, x1, x2 * x2));
        short sh0, sl0, sh1, sl1, sh2, sl2, rxh, rxl;
        split2(-2.f * x0, sh0, sl0);
        split2(-2.f * x1, sh1, sl1);
        split2(-2.f * x2, sh2, sl2);
        split2(rx, rxh, rxl);
        short8 h0, h1;
        h0[0] = sh0; h0[1] = sh1; h0[2] = sh2; h0[3] = sh0;
        h0[4] = sh1; h0[5] = sh2; h0[6] = sl0; h0[7] = sl1;
        h1[0] = sl2; h1[1] = sl0; h1[2] = sl1; h1[3] = sl2;
        h1[4] = rxh; h1[5] = rxl; h1[6] = 0;   h1[7] = 0;
        int slot = (p >> 5) * 64 + (p & 31);
        afr[slot]      = h0;
        afr[slot + 32] = h1;
    }

    // ---- B-side (query) fragments in registers ----
    short8 bfr[MPW];
    float  ry[MPW];
    const short ONE = 0x3F80;                // bf16 1.0
#pragma unroll
    for (int j = 0; j < MPW; ++j) {
        int mt = q * 16 + wid * 4 + j;
        int m  = mt * 32 + col;
        float y0 = qsrc[m], y1 = qsrc[PS + m], y2 = qsrc[2 * PS + m];
        ry[j] = fmaf(y0, y0, fmaf(y1, y1, y2 * y2));
        short yh0, yl0, yh1, yl1, yh2, yl2;
        split2(y0, yh0, yl0);
        split2(y1, yh1, yl1);
        split2(y2, yh2, yl2);
        short8 f;
        if (half == 0) {
            f[0] = yh0; f[1] = yh1; f[2] = yh2; f[3] = yl0;
            f[4] = yl1; f[5] = yl2; f[6] = yh0; f[7] = yh1;
        } else {
            f[0] = yh2; f[1] = yl0; f[2] = yl1; f[3] = yl2;
            f[4] = ONE; f[5] = ONE; f[6] = 0;   f[7] = 0;
        }
        bfr[j] = f;
    }
    __syncthreads();

    // ---- main loop: 32 ref tiles x MPW MFMAs, min-fold into acc ----
    float acc[MPW] = {3.4e38f, 3.4e38f, 3.4e38f, 3.4e38f};
    f32x16 zc = {};
#pragma unroll 4
    for (int nt = 0; nt < NT; ++nt) {
        short8 a = afr[nt * 64 + lane];
#pragma unroll
        for (int j = 0; j < MPW; ++j) {
            f32x16 d = __builtin_amdgcn_mfma_f32_32x32x16_bf16(a, bfr[j], zc, 0, 0, 0);
            // two parallel min3 chains (depth ~5) instead of one serial chain
            float c0 = fminf(fminf(d[0], d[1]), d[2]);
            c0 = fminf(fminf(c0, d[3]), d[4]);
            c0 = fminf(fminf(c0, d[5]), d[6]);
            float c1 = fminf(fminf(d[7], d[8]), d[9]);
            c1 = fminf(fminf(c1, d[10]), d[11]);
            c1 = fminf(fminf(c1, d[12]), d[13]);
            float c2 = fminf(fminf(acc[j], d[14]), d[15]);
            acc[j] = fminf(fminf(c0, c1), c2);
        }
    }

    // ---- per-query colmin write (lane-half 0 only; +ry so halves combine) ----
#pragma unroll
    for (int j = 0; j < MPW; ++j) {
        float v = acc[j];
        v = fminf(v, __shfl_xor(v, 32, 64));   // combine row-halves
        if (half == 0)
            pmin[(size_t)blk * 512 + (wid * 4 + j) * 32 + col] = v + ry[j];
    }
}

// finishA: 256 blocks; min-combine ref-halves, partial-sum per block.
__global__ __launch_bounds__(THREADS)
void finishA_kernel(const float* __restrict__ pmin, float* __restrict__ pb)
{
    __shared__ float red[THREADS / 64];
    const int tid = threadIdx.x;
    const int c   = blockIdx.x * 2 + (tid >> 7);   // chunk id, 0..511
    const int qi  = (tid & 127) * 4;
    const float4 a = *(const float4*)(pmin + (size_t)(c * 2) * 512 + qi);
    const float4 b = *(const float4*)(pmin + (size_t)(c * 2 + 1) * 512 + qi);
    float s = fminf(a.x, b.x) + fminf(a.y, b.y) + fminf(a.z, b.z) + fminf(a.w, b.w);
#pragma unroll
    for (int o = 32; o > 0; o >>= 1) s += __shfl_down(s, o, 64);
    if ((tid & 63) == 0) red[tid >> 6] = s;
    __syncthreads();
    if (tid == 0) pb[blockIdx.x] = red[0] + red[1] + red[2] + red[3];
}

// finishB: one block; sum 256 partials, scale by 1/64 (mean over slices).
__global__ __launch_bounds__(THREADS)
void finishB_kernel(const float* __restrict__ pb, float* __restrict__ out)
{
    __shared__ float red[THREADS / 64];
    const int tid = threadIdx.x;
    float s = pb[tid];
#pragma unroll
    for (int o = 32; o > 0; o >>= 1) s += __shfl_down(s, o, 64);
    if ((tid & 63) == 0) red[tid >> 6] = s;
    __syncthreads();
    if (tid == 0) out[0] = (red[0] + red[1] + red[2] + red[3]) * (1.0f / 64.0f);
}

extern "C" void kernel_launch(void* const* d_in, const int* in_sizes, int n_in,
                              void* d_out, int out_size, void* d_ws, size_t ws_size,
                              hipStream_t stream) {
    const float* preds = (const float*)d_in[0];
    const float* gts   = (const float*)d_in[1];
    float* out  = (float*)d_out;
    float* pmin = (float*)d_ws;              // 524288 floats = 2 MB
    float* pb   = pmin + PQ;                 // 256 floats

    chamfer_kernel<<<NBLK, THREADS, 0, stream>>>(preds, gts, pmin);
    finishA_kernel<<<256, THREADS, 0, stream>>>(pmin, pb);
    finishB_kernel<<<1, THREADS, 0, stream>>>(pb, out);
}